// Round 1
// baseline (28.766 us; speedup 1.0000x reference)
//
#include <hip/hip_runtime.h>
#include <hip/hip_bf16.h>

// loss = N * sum(x*x) - sum_d (colsum_d)^2, x is (256, D=100000) fp32 row-major.
// One streaming pass: block = 4 row-groups x 64 col-lanes, each thread handles
// one float4 column-group over 64 rows. LDS reduce across row groups for the
// column sums; one float atomicAdd per block into d_out.

#define N_ROWS 256
#define ROW_GROUPS 4
#define ROWS_PER_GROUP 64

__global__ __launch_bounds__(256) void tpc_loss_kernel(
    const float* __restrict__ x, float* __restrict__ out, int D4, int D) {
  const int lane = threadIdx.x & 63;       // column lane within tile
  const int grp  = threadIdx.x >> 6;       // row group 0..3
  const long col4 = (long)blockIdx.x * 64 + lane;

  float4 s = make_float4(0.f, 0.f, 0.f, 0.f);
  float q = 0.f;

  if (col4 < D4) {
    const float* p = x + (size_t)grp * ROWS_PER_GROUP * D + (size_t)col4 * 4;
#pragma unroll 8
    for (int r = 0; r < ROWS_PER_GROUP; ++r) {
      float4 v = *reinterpret_cast<const float4*>(p + (size_t)r * D);
      s.x += v.x; s.y += v.y; s.z += v.z; s.w += v.w;
      q += v.x * v.x + v.y * v.y + v.z * v.z + v.w * v.w;
    }
  }

  // Wave-reduce q across the 64 lanes of this row-group's wave.
#pragma unroll
  for (int off = 32; off > 0; off >>= 1) q += __shfl_down(q, off, 64);

  __shared__ float4 sh_s[ROW_GROUPS][64];
  __shared__ float  sh_q[ROW_GROUPS];
  sh_s[grp][lane] = s;
  if (lane == 0) sh_q[grp] = q;
  __syncthreads();

  if (grp == 0) {
    float4 t0 = sh_s[0][lane];
    float4 t1 = sh_s[1][lane];
    float4 t2 = sh_s[2][lane];
    float4 t3 = sh_s[3][lane];
    float sx = t0.x + t1.x + t2.x + t3.x;
    float sy = t0.y + t1.y + t2.y + t3.y;
    float sz = t0.z + t1.z + t2.z + t3.z;
    float sw = t0.w + t1.w + t2.w + t3.w;
    // Invalid columns contributed s == 0, so ssq == 0 for them.
    float ssq = sx * sx + sy * sy + sz * sz + sw * sw;
#pragma unroll
    for (int off = 32; off > 0; off >>= 1) ssq += __shfl_down(ssq, off, 64);
    if (lane == 0) {
      float qtot = sh_q[0] + sh_q[1] + sh_q[2] + sh_q[3];
      atomicAdd(out, (float)N_ROWS * qtot - ssq);
    }
  }
}

extern "C" void kernel_launch(void* const* d_in, const int* in_sizes, int n_in,
                              void* d_out, int out_size, void* d_ws, size_t ws_size,
                              hipStream_t stream) {
  const float* x = (const float*)d_in[0];
  float* out = (float*)d_out;
  const int total = in_sizes[0];
  const int D = total / N_ROWS;   // 100000
  const int D4 = D / 4;           // 25000 (D divisible by 4)

  hipMemsetAsync(d_out, 0, sizeof(float) * out_size, stream);

  const int blocks = (D4 + 63) / 64;  // 391
  tpc_loss_kernel<<<blocks, 256, 0, stream>>>(x, out, D4, D);
}